// Round 3
// baseline (425.177 us; speedup 1.0000x reference)
//
#include <hip/hip_runtime.h>

#define NN 512       // nodes
#define BB_ 64       // batch
#define EE 32768     // edges
#define TT 50        // input channels
#define FF 32        // hidden channels

// total workspace floats needed
#define WS_FLOATS (2056 + 2 * EE + 2 * (BB_ * NN * FF) + BB_ * 256)

// ---------------- graph setup kernels ----------------

__global__ void k_zero_out(float* out, int n) {
    int i = blockIdx.x * blockDim.x + threadIdx.x;
    if (i < n) out[i] = 0.f;
}

__global__ void k_zero(float* deg, int* cnt, float* fc1o) {
    int i = blockIdx.x * blockDim.x + threadIdx.x;
    if (i < NN) { deg[i] = 0.f; cnt[i] = 0; }
    if (i < BB_ * 256) fc1o[i] = 0.f;
}

__global__ void k_deg_cnt(const int* __restrict__ ei,
                          const float* __restrict__ ew,
                          float* __restrict__ deg, int* __restrict__ cnt) {
    int e = blockIdx.x * blockDim.x + threadIdx.x;
    if (e >= EE) return;
    int s = ei[e] & (NN - 1), d = ei[EE + e] & (NN - 1);
    float w = ew[e];
    if (s != d) atomicAdd(&deg[s], w);
    atomicAdd(&cnt[d], 1);
}

__global__ void k_dinv(float* deg) {
    int i = threadIdx.x;   // 512 threads, 1 block
    float d = deg[i];
    deg[i] = (d > 0.f) ? rsqrtf(d) : 0.f;
}

__global__ void k_scan(const int* __restrict__ cnt, int* __restrict__ rowptr,
                       int* __restrict__ cursor) {
    __shared__ int s[NN];
    int t = threadIdx.x;   // 512 threads, 1 block
    int myc = cnt[t];
    s[t] = myc;
    __syncthreads();
    for (int off = 1; off < NN; off <<= 1) {
        int v = (t >= off) ? s[t - off] : 0;
        __syncthreads();
        s[t] += v;
        __syncthreads();
    }
    int excl = s[t] - myc;
    rowptr[t] = excl;
    cursor[t] = excl;
    if (t == NN - 1) rowptr[NN] = s[t];
}

__global__ void k_scatter(const int* __restrict__ ei,
                          const float* __restrict__ ew,
                          const float* __restrict__ dinv,
                          int* __restrict__ cursor,
                          int* __restrict__ csr_src, float* __restrict__ csr_norm) {
    int e = blockIdx.x * blockDim.x + threadIdx.x;
    if (e >= EE) return;
    int s = ei[e] & (NN - 1), d = ei[EE + e] & (NN - 1);
    float w = (s == d) ? 0.f : ew[e];
    float nm = -(dinv[s] * w * dinv[d]);
    int pos = atomicAdd(&cursor[d], 1);
    if (pos >= 0 && pos < EE) { csr_src[pos] = s; csr_norm[pos] = nm; }
}

// ---------------- fused ChebConv (K=2) layer ----------------
// grid (NN, 8); block 256 = 8 batches x 32 features.
// out[b,n,f] = [relu]( sum_c h[b,n,c] W0[c,f] + sum_c p[b,n,c] W1[c,f] + bias[f] )
// p[b,n,:]  = sum_{edges e with dst==n} norm[e] * h[b, src[e], :]
template<int CIN, bool RELU>
__global__ __launch_bounds__(256) void k_cheb(
        const float* __restrict__ h, const float* __restrict__ W,
        const float* __restrict__ bias, const int* __restrict__ rowptr,
        const int* __restrict__ csr_src, const float* __restrict__ csr_norm,
        float* __restrict__ hout) {
    constexpr int NACC = (CIN + 31) / 32;
    constexpr int BL = 8;                 // batches per block
    __shared__ float W0s[CIN * FF];
    __shared__ float W1s[CIN * FF];
    __shared__ float bs[FF];
    __shared__ float plds[BL][CIN];
    __shared__ float hlds[BL][CIN];

    const int n   = blockIdx.x;
    const int tid = threadIdx.x;
    const int bl  = tid >> 5;
    const int f   = tid & 31;
    const int b   = blockIdx.y * BL + bl;

    for (int i = tid; i < CIN * FF; i += 256) {
        W0s[i] = W[i];
        W1s[i] = W[CIN * FF + i];
    }
    if (tid < FF) bs[tid] = bias[tid];

    float acc[NACC];
#pragma unroll
    for (int j = 0; j < NACC; ++j) acc[j] = 0.f;

    const float* hb = h + (size_t)b * (NN * CIN);
    const int beg = rowptr[n], end = rowptr[n + 1];
    for (int i = beg; i < end; ++i) {
        const int   s  = csr_src[i] & (NN - 1);
        const float nm = csr_norm[i];
        const float* hr = hb + s * CIN;
#pragma unroll
        for (int j = 0; j < NACC; ++j) {
            const int c = f + 32 * j;
            if (c < CIN) acc[j] += nm * hr[c];
        }
    }
    const float* hn = hb + n * CIN;
#pragma unroll
    for (int j = 0; j < NACC; ++j) {
        const int c = f + 32 * j;
        if (c < CIN) { plds[bl][c] = acc[j]; hlds[bl][c] = hn[c]; }
    }
    __syncthreads();

    float o = bs[f];
#pragma unroll 2
    for (int c = 0; c < CIN; ++c)
        o = fmaf(hlds[bl][c], W0s[c * FF + f], fmaf(plds[bl][c], W1s[c * FF + f], o));
    if (RELU) o = fmaxf(o, 0.f);
    hout[((size_t)b * NN + n) * FF + f] = o;
}

// ---------------- FC1: (64,16384) @ (16384,256), K-split partials ----------------
// grid (64 col-tiles of 4, 8 K-splits of 2048); block 256 = 64 batches x 4 cols.
__global__ __launch_bounds__(256) void k_fc1(const float* __restrict__ A,
                                             const float* __restrict__ W,
                                             float* __restrict__ out) {
    __shared__ float As[64][68];
    __shared__ float Ws[64][4];
    const int tid  = threadIdx.x;
    const int m    = tid >> 2;
    const int j4   = tid & 3;
    const int jcol = blockIdx.x * 4 + j4;
    const int kb   = blockIdx.y * 2048;
    float acc = 0.f;
    for (int kt = 0; kt < 32; ++kt) {
        const int k0 = kb + kt * 64;
        __syncthreads();
#pragma unroll
        for (int u = 0; u < 16; ++u) {
            int idx = tid + u * 256;
            int r = idx >> 6, c = idx & 63;
            As[r][c] = A[(size_t)r * 16384 + k0 + c];
        }
        Ws[tid >> 2][tid & 3] = W[(size_t)(k0 + (tid >> 2)) * 256 + blockIdx.x * 4 + (tid & 3)];
        __syncthreads();
#pragma unroll
        for (int kk = 0; kk < 64; ++kk)
            acc = fmaf(As[m][kk], Ws[kk][j4], acc);
    }
    atomicAdd(&out[m * 256 + jcol], acc);
}

// ---------------- fused FC2 + FC3 ----------------
// grid 64 (batch); block 128. fc1 bias folded in here.
__global__ __launch_bounds__(128) void k_fc23(const float* __restrict__ fc1o,
        const float* __restrict__ b1, const float* __restrict__ W2,
        const float* __restrict__ b2, const float* __restrict__ W3,
        const float* __restrict__ b3, float* __restrict__ out) {
    __shared__ float row[128];
    const int m = blockIdx.x, j = threadIdx.x;
    const float* a = fc1o + m * 256;
    float acc = b2[j];
    for (int k = 0; k < 256; ++k)
        acc = fmaf(a[k] + b1[k], W2[k * 128 + j], acc);
    row[j] = acc;
    __syncthreads();
    const int w = j >> 6, l = j & 63;
    float s = row[l] * W3[l * 2 + w] + row[l + 64] * W3[(l + 64) * 2 + w];
#pragma unroll
    for (int off = 32; off > 0; off >>= 1)
        s += __shfl_down(s, off);
    if (l == 0) out[m * 2 + w] = s + b3[w];
}

// ---------------- launch ----------------

extern "C" void kernel_launch(void* const* d_in, const int* in_sizes, int n_in,
                              void* d_out, int out_size, void* d_ws, size_t ws_size,
                              hipStream_t stream) {
    float* outp = (float*)d_out;

    // Defensive: if workspace is too small, produce zeros (visible numeric
    // failure) instead of faulting the GPU.
    if (ws_size < (size_t)WS_FLOATS * sizeof(float)) {
        k_zero_out<<<(out_size + 255) / 256, 256, 0, stream>>>(outp, out_size);
        return;
    }

    const float* x  = (const float*)d_in[0];
    const int*   ei = (const int*)d_in[1];     // int64 in reference -> int32 from harness
    const float* ew = (const float*)d_in[2];
    const float* cW[6] = {(const float*)d_in[3], (const float*)d_in[5],
                          (const float*)d_in[7], (const float*)d_in[9],
                          (const float*)d_in[11], (const float*)d_in[13]};
    const float* cb[6] = {(const float*)d_in[4], (const float*)d_in[6],
                          (const float*)d_in[8], (const float*)d_in[10],
                          (const float*)d_in[12], (const float*)d_in[14]};
    const float* fc1W = (const float*)d_in[15];
    const float* fc1b = (const float*)d_in[16];
    const float* fc2W = (const float*)d_in[17];
    const float* fc2b = (const float*)d_in[18];
    const float* fc3W = (const float*)d_in[19];
    const float* fc3b = (const float*)d_in[20];

    float* ws = (float*)d_ws;
    // ws layout (4-byte units)
    float* deg      = ws;                       // 512
    int*   cnt      = (int*)(ws + 512);         // 512
    int*   rowptr   = (int*)(ws + 1024);        // 513 (pad to 520)
    int*   cursor   = (int*)(ws + 1544);        // 512
    int*   csr_src  = (int*)(ws + 2056);        // EE
    float* csr_norm = ws + 2056 + EE;           // EE
    float* hA       = ws + 2056 + 2 * EE;       // 64*512*32
    float* hB       = hA + (size_t)BB_ * NN * FF;
    float* fc1o     = hB + (size_t)BB_ * NN * FF; // 64*256

    // graph build
    k_zero<<<64, 256, 0, stream>>>(deg, cnt, fc1o);
    k_deg_cnt<<<EE / 256, 256, 0, stream>>>(ei, ew, deg, cnt);
    k_dinv<<<1, 512, 0, stream>>>(deg);
    k_scan<<<1, 512, 0, stream>>>(cnt, rowptr, cursor);
    k_scatter<<<EE / 256, 256, 0, stream>>>(ei, ew, deg, cursor, csr_src, csr_norm);

    // 6 ChebConv layers
    dim3 cgrid(NN, BB_ / 8);
    k_cheb<TT, true ><<<cgrid, 256, 0, stream>>>(x,  cW[0], cb[0], rowptr, csr_src, csr_norm, hA);
    k_cheb<FF, true ><<<cgrid, 256, 0, stream>>>(hA, cW[1], cb[1], rowptr, csr_src, csr_norm, hB);
    k_cheb<FF, true ><<<cgrid, 256, 0, stream>>>(hB, cW[2], cb[2], rowptr, csr_src, csr_norm, hA);
    k_cheb<FF, true ><<<cgrid, 256, 0, stream>>>(hA, cW[3], cb[3], rowptr, csr_src, csr_norm, hB);
    k_cheb<FF, true ><<<cgrid, 256, 0, stream>>>(hB, cW[4], cb[4], rowptr, csr_src, csr_norm, hA);
    k_cheb<FF, false><<<cgrid, 256, 0, stream>>>(hA, cW[5], cb[5], rowptr, csr_src, csr_norm, hB);

    // FC head
    dim3 fgrid(64, 8);
    k_fc1<<<fgrid, 256, 0, stream>>>(hB, fc1W, fc1o);
    k_fc23<<<64, 128, 0, stream>>>(fc1o, fc1b, fc2W, fc2b, fc3W, fc3b, outp);
}